// Round 7
// baseline (174.447 us; speedup 1.0000x reference)
//
#include <hip/hip_runtime.h>
#include <math.h>

typedef unsigned int u32;
typedef unsigned long long u64;
typedef int v16i __attribute__((ext_vector_type(16)));

#define B 8
#define H 1024
#define W 1536
#define NPIX (H * W)
#define NK 2048
#define BORDER 16
#define NSEG 64
#define TY 8
#define NTILE 6            // W / 256
#define GRIDY 31           // 992 rows / (TY * 4 waves)
#define HBINS 512
#define TOPK_CAP 4096
#define SEG_CAP_MAX 4096
#define CTR_PAD 32
#define IDX_MASK 0x1FFFFFu

// workspace layout (bytes) — [0, OFF_ZERO_END) is zeroed by one memset.
// keys IS pre-zeroed (costs +256 KB on a 6.6 TB/s fill = ~0.04 us):
// rankref_k's scalar-pipe loads then need NO masking instructions at all.
#define OFF_TCOUNT 128      // u32[B*CTR_PAD]            ends 1152
#define OFF_HIST   4096     // u32[B*HBINS]              ends 20480
#define OFF_SEGCNT 20480    // u32[B*NSEG*CTR_PAD]       ends 86016
#define OFF_KEYS   86016    // u64[B*TOPK_CAP]           ends 348160
#define OFF_ZERO_END 348160
#define OFF_CAND   348160   // u32[B*NSEG*seg_cap]

__global__ __launch_bounds__(256) void cand_k(const float* __restrict__ neur,
                                              const float* __restrict__ score,
                                              u32* __restrict__ candp,
                                              u32* __restrict__ segcnt,
                                              u32* __restrict__ hist, int seg_cap) {
    __shared__ u32 lh[HBINS];
    int tile = blockIdx.x;
    int b = blockIdx.z;
    int wave = threadIdx.x >> 6;
    int lane = threadIdx.x & 63;
    for (int i = threadIdx.x; i < HBINS; i += 256) lh[i] = 0;
    __syncthreads();

    int strip = blockIdx.y * 4 + wave;
    int y0 = BORDER + strip * TY;
    int x0 = tile * 256 + lane * 4;
    const float* s = score + (size_t)b * NPIX;
    const float* nb = neur + (size_t)b * NPIX;
    bool haveL = (tile > 0) && (lane == 0);
    bool haveR = (tile < NTILE - 1) && (lane == 63);

    // preload: 10 score rows + 8 neur rows, all independent (one vmcnt burst)
    float4 rv[TY + 2];
    float4 nvv[TY];
    float le[TY + 2], re[TY + 2];
    const float* base_row = s + (size_t)(y0 - 1) * W + x0;
    const float* nrow = nb + (size_t)y0 * W + x0;
    #pragma unroll
    for (int r = 0; r < TY + 2; ++r) rv[r] = *(const float4*)(base_row + (size_t)r * W);
    #pragma unroll
    for (int r = 0; r < TY; ++r) nvv[r] = *(const float4*)(nrow + (size_t)r * W);
    #pragma unroll
    for (int r = 0; r < TY + 2; ++r) {
        le[r] = haveL ? base_row[(size_t)r * W - 1] : 0.0f;
        re[r] = haveR ? base_row[(size_t)r * W + 4] : 0.0f;
    }

    bool xok[4];
    #pragma unroll
    for (int e = 0; e < 4; ++e) {
        int x = x0 + e;
        xok[e] = (x >= BORDER) && (x < W - BORDER);
    }

    // phase A: pure register compute of all ext bits
    u32 extbits = 0;
    {
        float4 hm, h0, hp;
        #pragma unroll
        for (int r = 0; r < 2; ++r) {
            float4 c = rv[r];
            float l = __shfl_up(c.w, 1); if (haveL) l = le[r];
            float rr = __shfl_down(c.x, 1); if (haveR) rr = re[r];
            float4 hh;
            hh.x = fmaxf(fmaxf(l, c.x), c.y);
            hh.y = fmaxf(fmaxf(c.x, c.y), c.z);
            hh.z = fmaxf(fmaxf(c.y, c.z), c.w);
            hh.w = fmaxf(fmaxf(c.z, c.w), rr);
            if (r == 0) hm = hh; else h0 = hh;
        }
        #pragma unroll
        for (int ys = 0; ys < TY; ++ys) {
            float4 c = rv[ys + 2];
            float l = __shfl_up(c.w, 1); if (haveL) l = le[ys + 2];
            float rr = __shfl_down(c.x, 1); if (haveR) rr = re[ys + 2];
            hp.x = fmaxf(fmaxf(l, c.x), c.y);
            hp.y = fmaxf(fmaxf(c.x, c.y), c.z);
            hp.z = fmaxf(fmaxf(c.y, c.z), c.w);
            hp.w = fmaxf(fmaxf(c.z, c.w), rr);
            float pv[4];
            pv[0] = fmaxf(fmaxf(hm.x, h0.x), hp.x);
            pv[1] = fmaxf(fmaxf(hm.y, h0.y), hp.y);
            pv[2] = fmaxf(fmaxf(hm.z, h0.z), hp.z);
            pv[3] = fmaxf(fmaxf(hm.w, h0.w), hp.w);
            float4 c0 = rv[ys + 1];
            float cv[4] = {c0.x, c0.y, c0.z, c0.w};
            #pragma unroll
            for (int e = 0; e < 4; ++e)
                if (xok[e] && cv[e] >= pv[e]) extbits |= (1u << (ys * 4 + e));
            hm = h0; h0 = hp;
        }
    }

    // phase B: one wave scan + one leader atomic; nv already in registers
    u32 c = (u32)__popc(extbits);
    u32 scan = c;
    #pragma unroll
    for (int off = 1; off < 64; off <<= 1) {
        u32 o = (u32)__shfl_up((int)scan, off, 64);
        if (lane >= off) scan += o;
    }
    u32 excl = scan - c;
    u32 tot = (u32)__shfl((int)scan, 63, 64);
    if (tot) {
        int seg = (strip * NTILE + tile) & (NSEG - 1);
        u32* ctr = &segcnt[(u32)(b * NSEG + seg) * CTR_PAD];
        u32 base = 0;
        if (lane == 63) base = atomicAdd(ctr, scan);
        base = (u32)__shfl((int)base, 63, 64);
        u32 pos0 = base + excl;
        u32 sbase = (u32)(b * NSEG + seg) * (u32)seg_cap;
        u32 idxbase = (u32)(y0 * W + x0);
        #pragma unroll
        for (int k = 0; k < 32; ++k) {
            if (extbits & (1u << k)) {
                const int ro = k >> 2, e = k & 3;
                float4 nq = nvv[ro];
                float raw = (e == 0) ? nq.x : (e == 1) ? nq.y : (e == 2) ? nq.z : nq.w;
                float nv = fmaxf(raw, 0.0f);
                u32 fb = __float_as_uint(nv);
                u32 bin = fb >> 21; if (bin > HBINS - 1) bin = HBINS - 1;
                atomicAdd(&lh[bin], 1u);
                u32 idx = idxbase + (u32)ro * W + (u32)e;
                u32 p = pos0 + (u32)__popc(extbits & ((1u << k) - 1u));
                if ((int)p < seg_cap) candp[sbase + p] = (bin << 21) | idx;
            }
        }
    }
    __syncthreads();
    for (int i = threadIdx.x; i < HBINS; i += 256) {
        u32 v = lh[i];
        if (v) atomicAdd(&hist[(u32)b * HBINS + i], v);
    }
}

__global__ __launch_bounds__(256) void compact_k(const u32* __restrict__ candp,
                                                 const u32* __restrict__ segcnt,
                                                 const u32* __restrict__ hist,
                                                 const float* __restrict__ neur,
                                                 u64* __restrict__ keysout,
                                                 u32* tcount, int seg_cap) {
    __shared__ u32 piv_s;
    int seg = blockIdx.x;
    int b = blockIdx.y;
    int lane = threadIdx.x & 63;
    // wave 0: recompute pivot from hist (512 bins, 8/lane + shfl scan)
    if (threadIdx.x < 64) {
        if (threadIdx.x == 0) piv_s = 0xFFFFFFFFu;
        u32 v[8];
        u32 s8 = 0;
        #pragma unroll
        for (int e = 0; e < 8; ++e) {
            v[e] = hist[(u32)b * HBINS + (u32)threadIdx.x * 8u + e];
            s8 += v[e];
        }
        u32 incl = s8;
        #pragma unroll
        for (int off = 1; off < 64; off <<= 1) {
            u32 o = (u32)__shfl_up((int)incl, off, 64);
            if (lane >= off) incl += o;
        }
        u32 excl = incl - s8;
        if (excl < NK && incl >= NK) {
            u32 cum = excl;
            u32 T = 0;
            #pragma unroll
            for (int e = 0; e < 8; ++e) {
                cum += v[e];
                if (cum >= NK) { T = (u32)threadIdx.x * 8u + e; break; }
            }
            // bins <= T suffice: cum_{T-1} < NK <= cum_T means every top-NK
            // key has bin <= T, and excluded keys (bin > T) can never
            // outrank a kept key. (Was T+2 — over-selected by ~1-2 bins,
            // inflating the rank matrix by ~25-45%.)
            piv_s = (T + 1u) << 21;
        }
    }
    __syncthreads();
    u32 piv = piv_s;
    const float* nb = neur + (size_t)b * NPIX;

    u32 cnt = segcnt[(u32)(b * NSEG + seg) * CTR_PAD];
    if ((int)cnt > seg_cap) cnt = (u32)seg_cap;
    u32 base = (u32)(b * NSEG + seg) * (u32)seg_cap;
    u32 iters = (cnt + 255u) / 256u;
    for (u32 it = 0; it < iters; ++it) {
        u32 i = it * 256u + threadIdx.x;
        bool f = false;
        u32 idx = 0;
        if (i < cnt) {
            u32 p = candp[base + i];
            f = (p < piv);
            idx = p & IDX_MASK;
        }
        u64 m = __ballot((int)f);
        if (m) {
            int leader = __ffsll((long long)m) - 1;
            u32 wbase = 0;
            if (lane == leader) wbase = atomicAdd(&tcount[b * CTR_PAD], (u32)__popcll(m));
            wbase = (u32)__shfl((int)wbase, leader, 64);
            if (f) {
                u32 pos = wbase + (u32)__popcll(m & ((1ull << (u32)lane) - 1ull));
                if (pos < TOPK_CAP) {
                    float nv = fmaxf(nb[idx], 0.0f);
                    float ness = (float)exp(-(double)nv);  // correctly-rounded f32 exp
                    keysout[(u32)b * TOPK_CAP + pos] =
                        ((u64)__float_as_uint(ness) << 32) | (u32)(~idx);
                }
            }
        }
    }
}

// fused exact-rank + Taylor refine, scalar-memory-broadcast form with
// DYNAMIC bounds. Round-6 analysis: both broadcast forms stalled at
// ~24 us because they scan the full 4096x4096 zero-padded matrix while
// only ~cnt x cnt (~2700^2 with the T+1 pivot) is live. Three cuts:
// (1) blocks whose 64-i range is entirely >= cnt exit immediately
//     (uniform condition, before any sync);
// (2) per-wave j-group count ng = ceil((cnt - jbase)/8), capped 64 —
//     skipped groups compared zeros (guaranteed 0 contribution);
// (3) compact's pivot tightened T+2 -> T+1 shrinks cnt itself.
// Work scales ~(cnt/4096)^2 ~= 0.42x. Inner loop unchanged: 8 keys per
// s_load_dwordx16 + fused lgkmcnt(0) (SMEM completes out-of-order;
// data-dependence keeps uses below the wait [rule #18]); per j:
// v_cmp_gt_u64 (sgpr-pair vs vgpr-pair) + addc, 4 rotating accumulators.
// rank[i] = #{j : key_j > key_i}; keys distinct; valid keys > 0; pad
// zeros contribute 0 under strict >; pad own-keys cut by i >= cnt.
__global__ __launch_bounds__(512, 1) void rankref_k(const float* __restrict__ neur,
                                                    const float* __restrict__ score,
                                                    const u64* __restrict__ keys,
                                                    const u32* __restrict__ tcount,
                                                    float* __restrict__ out) {
    __shared__ u32 part[7][64];
    int b = blockIdx.y;
    int wave = threadIdx.x >> 6;
    int lane = threadIdx.x & 63;
    u32 cnt = tcount[(u32)b * CTR_PAD];
    if (cnt > TOPK_CAP) cnt = TOPK_CAP;
    if (blockIdx.x * 64u >= cnt) return;   // whole block is pad: nothing to rank
    const u64* kb = keys + (u32)b * TOPK_CAP;

    // lane's own i-key (same 64 i-keys for all 8 waves of the block);
    // always in-bounds, tail is zero-padded
    u32 i = blockIdx.x * 64u + (u32)lane;
    u64 kown = kb[i];

    // this wave's j-range: up to 512 j = 64 groups of 8 keys; pointer
    // made uniform so the asm "s" constraint is legal
    u32 jbase = (u32)wave * 512u;
    int remj = (int)cnt - (int)jbase;
    int ng = remj <= 0 ? 0 : (remj >= 512 ? 64 : ((remj + 7) >> 3));
    uintptr_t p = (uintptr_t)(kb + jbase);
    u32 plo = (u32)__builtin_amdgcn_readfirstlane((int)(u32)p);
    u32 phi = (u32)__builtin_amdgcn_readfirstlane((int)(u32)(p >> 32));
    const u64* kqu = (const u64*)(((uintptr_t)phi << 32) | (uintptr_t)plo);

    u32 r0 = 0, r1 = 0, r2 = 0, r3 = 0;
    #pragma unroll 2
    for (int g = 0; g < ng; ++g) {
        v16i kk;
        asm volatile("s_load_dwordx16 %0, %1, 0x0\n\ts_waitcnt lgkmcnt(0)"
                     : "=s"(kk)
                     : "s"(kqu + (size_t)g * 8)
                     : "memory");
        u64 k0 = ((u64)(u32)kk[1]  << 32) | (u64)(u32)kk[0];
        u64 k1 = ((u64)(u32)kk[3]  << 32) | (u64)(u32)kk[2];
        u64 k2 = ((u64)(u32)kk[5]  << 32) | (u64)(u32)kk[4];
        u64 k3 = ((u64)(u32)kk[7]  << 32) | (u64)(u32)kk[6];
        u64 k4 = ((u64)(u32)kk[9]  << 32) | (u64)(u32)kk[8];
        u64 k5 = ((u64)(u32)kk[11] << 32) | (u64)(u32)kk[10];
        u64 k6 = ((u64)(u32)kk[13] << 32) | (u64)(u32)kk[12];
        u64 k7 = ((u64)(u32)kk[15] << 32) | (u64)(u32)kk[14];
        r0 += (k0 > kown) ? 1u : 0u;
        r1 += (k1 > kown) ? 1u : 0u;
        r2 += (k2 > kown) ? 1u : 0u;
        r3 += (k3 > kown) ? 1u : 0u;
        r0 += (k4 > kown) ? 1u : 0u;
        r1 += (k5 > kown) ? 1u : 0u;
        r2 += (k6 > kown) ? 1u : 0u;
        r3 += (k7 > kown) ? 1u : 0u;
    }
    u32 myrank = (r0 + r1) + (r2 + r3);

    if (wave) part[wave - 1][lane] = myrank;
    __syncthreads();
    if (wave) return;
    #pragma unroll
    for (int wv = 0; wv < 7; ++wv) myrank += part[wv][lane];

    if (i >= cnt || myrank >= NK) return;

    u32 idx = ~(u32)kown;
    if (idx >= (u32)NPIX) return;  // defensive: never true for legitimate keys
    const float* s = score + (size_t)b * NPIX;
    const float* nb = neur + (size_t)b * NPIX;
    int y = (int)(idx / W), x = (int)(idx % W);
    int yc = min(max(y, 1), H - 2), xc = min(max(x, 1), W - 2);
    int pp = yc * W + xc;
    float s00 = s[pp], sp0 = s[pp + W], sm0 = s[pp - W], s0p = s[pp + 1], s0m = s[pp - 1];
    float spp = s[pp + W + 1], spm = s[pp + W - 1], smp = s[pp - W + 1], smm = s[pp - W - 1];
    float gy = 0.5f * (sp0 - sm0);
    float gx = 0.5f * (s0p - s0m);
    float hyy = sp0 - 2.0f * s00 + sm0;
    float hxx = s0p - 2.0f * s00 + s0m;
    float hxy = 0.25f * (spp - spm - smp + smm);
    float det = hyy * hxx - hxy * hxy;
    bool sing = fabsf(det) > 1e-12f;
    float sd = sing ? det : 1.0f;
    float iy = -(hxx * gy - hxy * gx) / sd;
    float ix = -(hyy * gx - hxy * gy) / sd;
    if (!sing) { iy = 0.0f; ix = 0.0f; }
    iy = fminf(fmaxf(iy, -0.5f), 0.5f);
    ix = fminf(fmaxf(ix, -0.5f), 0.5f);
    size_t o = ((size_t)b * NK + (size_t)myrank) * 3;
    out[o] = (float)y + 0.5f + iy;
    out[o + 1] = (float)x + 0.5f + ix;
    out[o + 2] = fmaxf(nb[idx], 0.0f);
}

extern "C" void kernel_launch(void* const* d_in, const int* in_sizes, int n_in,
                              void* d_out, int out_size, void* d_ws, size_t ws_size,
                              hipStream_t stream) {
    const float* neur = (const float*)d_in[0];
    const float* score = (const float*)d_in[1];
    float* out = (float*)d_out;
    char* ws = (char*)d_ws;
    u32* tcount = (u32*)(ws + OFF_TCOUNT);
    u32* hist = (u32*)(ws + OFF_HIST);
    u32* segcnt = (u32*)(ws + OFF_SEGCNT);
    u64* keysbuf = (u64*)(ws + OFF_KEYS);
    u32* candp = (u32*)(ws + OFF_CAND);

    size_t avail = ws_size > OFF_CAND ? ws_size - OFF_CAND : 0;
    long long cap_ll = (long long)(avail / (4ull * B * NSEG));
    int seg_cap = cap_ll > SEG_CAP_MAX ? SEG_CAP_MAX : (int)cap_ll;

    // zero tcount/hist/segcnt/keys in one memset node
    hipMemsetAsync(ws, 0, OFF_ZERO_END, stream);
    cand_k<<<dim3(NTILE, GRIDY, B), 256, 0, stream>>>(neur, score, candp, segcnt, hist, seg_cap);
    compact_k<<<dim3(NSEG, B), 256, 0, stream>>>(candp, segcnt, hist, neur, keysbuf, tcount, seg_cap);
    rankref_k<<<dim3(TOPK_CAP / 64, B), 512, 0, stream>>>(neur, score, keysbuf, tcount, out);
}

// Round 8
// 160.322 us; speedup vs baseline: 1.0881x; 1.0881x over previous
//
#include <hip/hip_runtime.h>
#include <math.h>

typedef unsigned int u32;
typedef unsigned long long u64;
typedef int v16i __attribute__((ext_vector_type(16)));

#define B 8
#define H 1024
#define W 1536
#define NPIX (H * W)
#define NK 2048
#define BORDER 16
#define NSEG 64
#define TY 8
#define NTILE 6            // W / 256
#define GRIDY 31           // 992 rows / (TY * 4 waves)
#define HBINS 512
#define TOPK_CAP 4096
#define SEG_CAP_MAX 4096
#define CTR_PAD 32
#define IDX_MASK 0x1FFFFFu

// workspace layout (bytes) — [0, OFF_ZERO_END) is zeroed by one memset.
// keys IS pre-zeroed (costs +256 KB on a 6.6 TB/s fill = ~0.04 us):
// rankref_k's scalar-pipe loads then need NO masking instructions at all,
// and over-reads in the rounded-up group count compare zeros (contribute 0).
#define OFF_TCOUNT 128      // u32[B*CTR_PAD]            ends 1152
#define OFF_HIST   4096     // u32[B*HBINS]              ends 20480
#define OFF_SEGCNT 20480    // u32[B*NSEG*CTR_PAD]       ends 86016
#define OFF_KEYS   86016    // u64[B*TOPK_CAP]           ends 348160
#define OFF_ZERO_END 348160
#define OFF_CAND   348160   // u32[B*NSEG*seg_cap]

__global__ __launch_bounds__(256) void cand_k(const float* __restrict__ neur,
                                              const float* __restrict__ score,
                                              u32* __restrict__ candp,
                                              u32* __restrict__ segcnt,
                                              u32* __restrict__ hist, int seg_cap) {
    __shared__ u32 lh[HBINS];
    int tile = blockIdx.x;
    int b = blockIdx.z;
    int wave = threadIdx.x >> 6;
    int lane = threadIdx.x & 63;
    for (int i = threadIdx.x; i < HBINS; i += 256) lh[i] = 0;
    __syncthreads();

    int strip = blockIdx.y * 4 + wave;
    int y0 = BORDER + strip * TY;
    int x0 = tile * 256 + lane * 4;
    const float* s = score + (size_t)b * NPIX;
    const float* nb = neur + (size_t)b * NPIX;
    bool haveL = (tile > 0) && (lane == 0);
    bool haveR = (tile < NTILE - 1) && (lane == 63);

    // preload: 10 score rows + 8 neur rows, all independent (one vmcnt burst)
    float4 rv[TY + 2];
    float4 nvv[TY];
    float le[TY + 2], re[TY + 2];
    const float* base_row = s + (size_t)(y0 - 1) * W + x0;
    const float* nrow = nb + (size_t)y0 * W + x0;
    #pragma unroll
    for (int r = 0; r < TY + 2; ++r) rv[r] = *(const float4*)(base_row + (size_t)r * W);
    #pragma unroll
    for (int r = 0; r < TY; ++r) nvv[r] = *(const float4*)(nrow + (size_t)r * W);
    #pragma unroll
    for (int r = 0; r < TY + 2; ++r) {
        le[r] = haveL ? base_row[(size_t)r * W - 1] : 0.0f;
        re[r] = haveR ? base_row[(size_t)r * W + 4] : 0.0f;
    }

    bool xok[4];
    #pragma unroll
    for (int e = 0; e < 4; ++e) {
        int x = x0 + e;
        xok[e] = (x >= BORDER) && (x < W - BORDER);
    }

    // phase A: pure register compute of all ext bits
    u32 extbits = 0;
    {
        float4 hm, h0, hp;
        #pragma unroll
        for (int r = 0; r < 2; ++r) {
            float4 c = rv[r];
            float l = __shfl_up(c.w, 1); if (haveL) l = le[r];
            float rr = __shfl_down(c.x, 1); if (haveR) rr = re[r];
            float4 hh;
            hh.x = fmaxf(fmaxf(l, c.x), c.y);
            hh.y = fmaxf(fmaxf(c.x, c.y), c.z);
            hh.z = fmaxf(fmaxf(c.y, c.z), c.w);
            hh.w = fmaxf(fmaxf(c.z, c.w), rr);
            if (r == 0) hm = hh; else h0 = hh;
        }
        #pragma unroll
        for (int ys = 0; ys < TY; ++ys) {
            float4 c = rv[ys + 2];
            float l = __shfl_up(c.w, 1); if (haveL) l = le[ys + 2];
            float rr = __shfl_down(c.x, 1); if (haveR) rr = re[ys + 2];
            hp.x = fmaxf(fmaxf(l, c.x), c.y);
            hp.y = fmaxf(fmaxf(c.x, c.y), c.z);
            hp.z = fmaxf(fmaxf(c.y, c.z), c.w);
            hp.w = fmaxf(fmaxf(c.z, c.w), rr);
            float pv[4];
            pv[0] = fmaxf(fmaxf(hm.x, h0.x), hp.x);
            pv[1] = fmaxf(fmaxf(hm.y, h0.y), hp.y);
            pv[2] = fmaxf(fmaxf(hm.z, h0.z), hp.z);
            pv[3] = fmaxf(fmaxf(hm.w, h0.w), hp.w);
            float4 c0 = rv[ys + 1];
            float cv[4] = {c0.x, c0.y, c0.z, c0.w};
            #pragma unroll
            for (int e = 0; e < 4; ++e)
                if (xok[e] && cv[e] >= pv[e]) extbits |= (1u << (ys * 4 + e));
            hm = h0; h0 = hp;
        }
    }

    // phase B: one wave scan + one leader atomic; nv already in registers
    u32 c = (u32)__popc(extbits);
    u32 scan = c;
    #pragma unroll
    for (int off = 1; off < 64; off <<= 1) {
        u32 o = (u32)__shfl_up((int)scan, off, 64);
        if (lane >= off) scan += o;
    }
    u32 excl = scan - c;
    u32 tot = (u32)__shfl((int)scan, 63, 64);
    if (tot) {
        int seg = (strip * NTILE + tile) & (NSEG - 1);
        u32* ctr = &segcnt[(u32)(b * NSEG + seg) * CTR_PAD];
        u32 base = 0;
        if (lane == 63) base = atomicAdd(ctr, scan);
        base = (u32)__shfl((int)base, 63, 64);
        u32 pos0 = base + excl;
        u32 sbase = (u32)(b * NSEG + seg) * (u32)seg_cap;
        u32 idxbase = (u32)(y0 * W + x0);
        #pragma unroll
        for (int k = 0; k < 32; ++k) {
            if (extbits & (1u << k)) {
                const int ro = k >> 2, e = k & 3;
                float4 nq = nvv[ro];
                float raw = (e == 0) ? nq.x : (e == 1) ? nq.y : (e == 2) ? nq.z : nq.w;
                float nv = fmaxf(raw, 0.0f);
                u32 fb = __float_as_uint(nv);
                u32 bin = fb >> 21; if (bin > HBINS - 1) bin = HBINS - 1;
                atomicAdd(&lh[bin], 1u);
                u32 idx = idxbase + (u32)ro * W + (u32)e;
                u32 p = pos0 + (u32)__popc(extbits & ((1u << k) - 1u));
                if ((int)p < seg_cap) candp[sbase + p] = (bin << 21) | idx;
            }
        }
    }
    __syncthreads();
    for (int i = threadIdx.x; i < HBINS; i += 256) {
        u32 v = lh[i];
        if (v) atomicAdd(&hist[(u32)b * HBINS + i], v);
    }
}

__global__ __launch_bounds__(256) void compact_k(const u32* __restrict__ candp,
                                                 const u32* __restrict__ segcnt,
                                                 const u32* __restrict__ hist,
                                                 const float* __restrict__ neur,
                                                 u64* __restrict__ keysout,
                                                 u32* tcount, int seg_cap) {
    __shared__ u32 piv_s;
    int seg = blockIdx.x;
    int b = blockIdx.y;
    int lane = threadIdx.x & 63;
    // wave 0: recompute pivot from hist (512 bins, 8/lane + shfl scan)
    if (threadIdx.x < 64) {
        if (threadIdx.x == 0) piv_s = 0xFFFFFFFFu;
        u32 v[8];
        u32 s8 = 0;
        #pragma unroll
        for (int e = 0; e < 8; ++e) {
            v[e] = hist[(u32)b * HBINS + (u32)threadIdx.x * 8u + e];
            s8 += v[e];
        }
        u32 incl = s8;
        #pragma unroll
        for (int off = 1; off < 64; off <<= 1) {
            u32 o = (u32)__shfl_up((int)incl, off, 64);
            if (lane >= off) incl += o;
        }
        u32 excl = incl - s8;
        if (excl < NK && incl >= NK) {
            u32 cum = excl;
            u32 T = 0;
            #pragma unroll
            for (int e = 0; e < 8; ++e) {
                cum += v[e];
                if (cum >= NK) { T = (u32)threadIdx.x * 8u + e; break; }
            }
            // bins <= T suffice: cum_{T-1} < NK <= cum_T means every top-NK
            // key has bin <= T, and excluded keys (bin > T) can never
            // outrank a kept key.
            piv_s = (T + 1u) << 21;
        }
    }
    __syncthreads();
    u32 piv = piv_s;
    const float* nb = neur + (size_t)b * NPIX;

    u32 cnt = segcnt[(u32)(b * NSEG + seg) * CTR_PAD];
    if ((int)cnt > seg_cap) cnt = (u32)seg_cap;
    u32 base = (u32)(b * NSEG + seg) * (u32)seg_cap;
    u32 iters = (cnt + 255u) / 256u;
    for (u32 it = 0; it < iters; ++it) {
        u32 i = it * 256u + threadIdx.x;
        bool f = false;
        u32 idx = 0;
        if (i < cnt) {
            u32 p = candp[base + i];
            f = (p < piv);
            idx = p & IDX_MASK;
        }
        u64 m = __ballot((int)f);
        if (m) {
            int leader = __ffsll((long long)m) - 1;
            u32 wbase = 0;
            if (lane == leader) wbase = atomicAdd(&tcount[b * CTR_PAD], (u32)__popcll(m));
            wbase = (u32)__shfl((int)wbase, leader, 64);
            if (f) {
                u32 pos = wbase + (u32)__popcll(m & ((1ull << (u32)lane) - 1ull));
                if (pos < TOPK_CAP) {
                    float nv = fmaxf(nb[idx], 0.0f);
                    float ness = (float)exp(-(double)nv);  // correctly-rounded f32 exp
                    keysout[(u32)b * TOPK_CAP + pos] =
                        ((u64)__float_as_uint(ness) << 32) | (u32)(~idx);
                }
            }
        }
    }
}

// fused exact-rank + Taylor refine, DEPTH-4 PIPELINED scalar-memory form.
// Round-7 null isolated the regime: rankref is bound by its per-wave
// SERIAL chain of SMEM round-trips (issue -> lgkmcnt(0) -> consume, one
// group at a time). The keys were written by compact_k on other XCDs;
// the kernel-boundary flush means every scalar load pays ~900 cyc (HBM):
// 64 trips x 900 = 24 us, and cutting compare WORK (R7) doesn't shorten
// the longest chain. Fix: batch FOUR s_load_dwordx16 in one asm block
// with a single s_waitcnt lgkmcnt(0) (wait-ALL is safe under SMEM's
// out-of-order completion; the fused wait + data-dependence keeps all
// consumption below it [rule #18]). Chain: 64 -> 16 round-trips
// ~= 16 x (900 + ~130 consume) ~= 6.9 us. SGPR cost: 4x16 keys = 64
// + ~20 overhead < 102 budget. ng rounds up to a multiple of 4 —
// over-read hits the pre-zeroed tail (<= key 4096, in-bounds),
// contributes 0 under strict >.
// rank[i] = #{j : key_j > key_i}; keys distinct; valid keys > 0; pad
// zeros contribute 0; pad own-keys cut by i >= cnt. Bit-identical.
__global__ __launch_bounds__(512, 1) void rankref_k(const float* __restrict__ neur,
                                                    const float* __restrict__ score,
                                                    const u64* __restrict__ keys,
                                                    const u32* __restrict__ tcount,
                                                    float* __restrict__ out) {
    __shared__ u32 part[7][64];
    int b = blockIdx.y;
    int wave = threadIdx.x >> 6;
    int lane = threadIdx.x & 63;
    u32 cnt = tcount[(u32)b * CTR_PAD];
    if (cnt > TOPK_CAP) cnt = TOPK_CAP;
    if (blockIdx.x * 64u >= cnt) return;   // whole block is pad: nothing to rank
    const u64* kb = keys + (u32)b * TOPK_CAP;

    // lane's own i-key (same 64 i-keys for all 8 waves of the block);
    // always in-bounds, tail is zero-padded
    u32 i = blockIdx.x * 64u + (u32)lane;
    u64 kown = kb[i];

    // this wave's j-range: up to 512 j = 64 groups of 8 keys, processed
    // 4 groups (32 keys) per pipelined phase; pointer made uniform so
    // the asm "s" constraint is legal
    u32 jbase = (u32)wave * 512u;
    int remj = (int)cnt - (int)jbase;
    int ng = remj <= 0 ? 0 : (remj >= 512 ? 64 : ((remj + 7) >> 3));
    ng = (ng + 3) & ~3;                    // round up: extra groups compare zeros
    uintptr_t p = (uintptr_t)(kb + jbase);
    u32 plo = (u32)__builtin_amdgcn_readfirstlane((int)(u32)p);
    u32 phi = (u32)__builtin_amdgcn_readfirstlane((int)(u32)(p >> 32));
    const u64* kqu = (const u64*)(((uintptr_t)phi << 32) | (uintptr_t)plo);

    u32 r0 = 0, r1 = 0, r2 = 0, r3 = 0;
    for (int g = 0; g < ng; g += 4) {
        v16i ka, kc, ke, kg;
        asm volatile("s_load_dwordx16 %0, %4, 0x0\n\t"
                     "s_load_dwordx16 %1, %4, 0x40\n\t"
                     "s_load_dwordx16 %2, %4, 0x80\n\t"
                     "s_load_dwordx16 %3, %4, 0xC0\n\t"
                     "s_waitcnt lgkmcnt(0)"
                     : "=s"(ka), "=s"(kc), "=s"(ke), "=s"(kg)
                     : "s"(kqu + (size_t)g * 8)
                     : "memory");
        #pragma unroll
        for (int q = 0; q < 4; ++q) {
            v16i kk = (q == 0) ? ka : (q == 1) ? kc : (q == 2) ? ke : kg;
            u64 k0 = ((u64)(u32)kk[1]  << 32) | (u64)(u32)kk[0];
            u64 k1 = ((u64)(u32)kk[3]  << 32) | (u64)(u32)kk[2];
            u64 k2 = ((u64)(u32)kk[5]  << 32) | (u64)(u32)kk[4];
            u64 k3 = ((u64)(u32)kk[7]  << 32) | (u64)(u32)kk[6];
            u64 k4 = ((u64)(u32)kk[9]  << 32) | (u64)(u32)kk[8];
            u64 k5 = ((u64)(u32)kk[11] << 32) | (u64)(u32)kk[10];
            u64 k6 = ((u64)(u32)kk[13] << 32) | (u64)(u32)kk[12];
            u64 k7 = ((u64)(u32)kk[15] << 32) | (u64)(u32)kk[14];
            r0 += (k0 > kown) ? 1u : 0u;
            r1 += (k1 > kown) ? 1u : 0u;
            r2 += (k2 > kown) ? 1u : 0u;
            r3 += (k3 > kown) ? 1u : 0u;
            r0 += (k4 > kown) ? 1u : 0u;
            r1 += (k5 > kown) ? 1u : 0u;
            r2 += (k6 > kown) ? 1u : 0u;
            r3 += (k7 > kown) ? 1u : 0u;
        }
    }
    u32 myrank = (r0 + r1) + (r2 + r3);

    if (wave) part[wave - 1][lane] = myrank;
    __syncthreads();
    if (wave) return;
    #pragma unroll
    for (int wv = 0; wv < 7; ++wv) myrank += part[wv][lane];

    if (i >= cnt || myrank >= NK) return;

    u32 idx = ~(u32)kown;
    if (idx >= (u32)NPIX) return;  // defensive: never true for legitimate keys
    const float* s = score + (size_t)b * NPIX;
    const float* nb = neur + (size_t)b * NPIX;
    int y = (int)(idx / W), x = (int)(idx % W);
    int yc = min(max(y, 1), H - 2), xc = min(max(x, 1), W - 2);
    int pp = yc * W + xc;
    float s00 = s[pp], sp0 = s[pp + W], sm0 = s[pp - W], s0p = s[pp + 1], s0m = s[pp - 1];
    float spp = s[pp + W + 1], spm = s[pp + W - 1], smp = s[pp - W + 1], smm = s[pp - W - 1];
    float gy = 0.5f * (sp0 - sm0);
    float gx = 0.5f * (s0p - s0m);
    float hyy = sp0 - 2.0f * s00 + sm0;
    float hxx = s0p - 2.0f * s00 + s0m;
    float hxy = 0.25f * (spp - spm - smp + smm);
    float det = hyy * hxx - hxy * hxy;
    bool sing = fabsf(det) > 1e-12f;
    float sd = sing ? det : 1.0f;
    float iy = -(hxx * gy - hxy * gx) / sd;
    float ix = -(hyy * gx - hxy * gy) / sd;
    if (!sing) { iy = 0.0f; ix = 0.0f; }
    iy = fminf(fmaxf(iy, -0.5f), 0.5f);
    ix = fminf(fmaxf(ix, -0.5f), 0.5f);
    size_t o = ((size_t)b * NK + (size_t)myrank) * 3;
    out[o] = (float)y + 0.5f + iy;
    out[o + 1] = (float)x + 0.5f + ix;
    out[o + 2] = fmaxf(nb[idx], 0.0f);
}

extern "C" void kernel_launch(void* const* d_in, const int* in_sizes, int n_in,
                              void* d_out, int out_size, void* d_ws, size_t ws_size,
                              hipStream_t stream) {
    const float* neur = (const float*)d_in[0];
    const float* score = (const float*)d_in[1];
    float* out = (float*)d_out;
    char* ws = (char*)d_ws;
    u32* tcount = (u32*)(ws + OFF_TCOUNT);
    u32* hist = (u32*)(ws + OFF_HIST);
    u32* segcnt = (u32*)(ws + OFF_SEGCNT);
    u64* keysbuf = (u64*)(ws + OFF_KEYS);
    u32* candp = (u32*)(ws + OFF_CAND);

    size_t avail = ws_size > OFF_CAND ? ws_size - OFF_CAND : 0;
    long long cap_ll = (long long)(avail / (4ull * B * NSEG));
    int seg_cap = cap_ll > SEG_CAP_MAX ? SEG_CAP_MAX : (int)cap_ll;

    // zero tcount/hist/segcnt/keys in one memset node
    hipMemsetAsync(ws, 0, OFF_ZERO_END, stream);
    cand_k<<<dim3(NTILE, GRIDY, B), 256, 0, stream>>>(neur, score, candp, segcnt, hist, seg_cap);
    compact_k<<<dim3(NSEG, B), 256, 0, stream>>>(candp, segcnt, hist, neur, keysbuf, tcount, seg_cap);
    rankref_k<<<dim3(TOPK_CAP / 64, B), 512, 0, stream>>>(neur, score, keysbuf, tcount, out);
}